// Round 1
// baseline (652.418 us; speedup 1.0000x reference)
//
#include <hip/hip_runtime.h>
#include <hip/hip_bf16.h>
#include <math.h>

// Problem constants (from reference)
#define N_TS 19000
#define T_DIM 168
#define U_DIM 256
#define NBLK 3
#define HORIZON 24

__device__ __forceinline__ float softplus_f(float z) {
    // jax.nn.softplus = logaddexp(z, 0) = max(z,0) + log1p(exp(-|z|))
    return fmaxf(z, 0.0f) + log1pf(__expf(-fabsf(z)));
}

// ---------------------------------------------------------------------------
// Precompute: Wvo[b] = Wo[b] @ Wv[b]  (row n of Wvo = row n of Wo times Wv)
//             bvo[b] = Wo[b] @ bv[b] + bo[b]
// grid: 3*256 blocks (b = blockIdx>>8, n = blockIdx&255), 256 threads (col j)
// ---------------------------------------------------------------------------
__global__ __launch_bounds__(256) void precompute_kernel(
    const float* __restrict__ Wv, const float* __restrict__ bv,
    const float* __restrict__ Wo, const float* __restrict__ bo,
    float* __restrict__ Wvo, float* __restrict__ bvo)
{
    const int n = blockIdx.x & 255;
    const int b = blockIdx.x >> 8;
    const int j = threadIdx.x;
    const float* Wo_row = Wo + ((size_t)b * U_DIM + n) * U_DIM;
    const float* Wv_b   = Wv + (size_t)b * U_DIM * U_DIM;

    float acc = 0.0f;
    for (int t = 0; t < U_DIM; ++t) {
        // Wo_row[t] is wave-uniform (scalar); Wv_b[t*U+j] is coalesced
        acc = fmaf(Wo_row[t], Wv_b[(size_t)t * U_DIM + j], acc);
    }
    Wvo[((size_t)b * U_DIM + n) * U_DIM + j] = acc;

    // bvo[b][n] = sum_t Wo[n][t]*bv[t] + bo[n]  (block reduction)
    __shared__ float red[256];
    red[j] = Wo_row[j] * bv[b * U_DIM + j];
    __syncthreads();
    for (int s = 128; s > 0; s >>= 1) {
        if (j < s) red[j] += red[j + s];
        __syncthreads();
    }
    if (j == 0) bvo[b * U_DIM + n] = red[0] + bo[b * U_DIM + n];
}

// ---------------------------------------------------------------------------
// C[M,N] = act( A[M,K] @ B[N,K]^T (+ bias[N]) (+ res[M,N]) )
// ACT: 0=none, 1=softplus.  f32, BM=BN=64, BK=32, 4x4 micro-tile/thread.
// ---------------------------------------------------------------------------
template<int ACT, bool HAS_BIAS, bool HAS_RES>
__global__ __launch_bounds__(256) void gemm_nt(
    const float* __restrict__ A, const float* __restrict__ B,
    const float* __restrict__ bias, const float* __restrict__ res,
    float* __restrict__ C, int M, int N, int K)
{
    constexpr int BM = 64, BN = 64, BK = 32;
    __shared__ float As[BK][BM + 4];   // +4 pad keeps float4 reads aligned
    __shared__ float Bs[BK][BN + 4];

    const int tid = threadIdx.x;
    const int tx = tid & 15;   // n-direction (16)
    const int ty = tid >> 4;   // m-direction (16)
    const int bm = blockIdx.x * BM;
    const int bn = blockIdx.y * BN;

    float acc[4][4] = {};

    const int nk = (K + BK - 1) / BK;
    for (int kt = 0; kt < nk; ++kt) {
        const int k0 = kt * BK;

        // Stage A tile: 64x32 floats = 512 float4s, 2 per thread
        #pragma unroll
        for (int i = 0; i < 2; ++i) {
            int f  = tid + i * 256;
            int m  = f >> 3;              // 0..63
            int kq = (f & 7) << 2;        // 0,4,...,28
            int gm = bm + m, gk = k0 + kq;
            float4 v = make_float4(0.f, 0.f, 0.f, 0.f);
            if (gm < M && gk + 3 < K)     // K%4==0 so float4 fully valid or not
                v = *(const float4*)&A[(size_t)gm * K + gk];
            As[kq + 0][m] = v.x; As[kq + 1][m] = v.y;
            As[kq + 2][m] = v.z; As[kq + 3][m] = v.w;
        }
        // Stage B tile
        #pragma unroll
        for (int i = 0; i < 2; ++i) {
            int f  = tid + i * 256;
            int n  = f >> 3;
            int kq = (f & 7) << 2;
            int gn = bn + n, gk = k0 + kq;
            float4 v = make_float4(0.f, 0.f, 0.f, 0.f);
            if (gn < N && gk + 3 < K)
                v = *(const float4*)&B[(size_t)gn * K + gk];
            Bs[kq + 0][n] = v.x; Bs[kq + 1][n] = v.y;
            Bs[kq + 2][n] = v.z; Bs[kq + 3][n] = v.w;
        }
        __syncthreads();

        #pragma unroll
        for (int kk = 0; kk < BK; ++kk) {
            float4 av = *(const float4*)&As[kk][ty << 2];
            float4 bv = *(const float4*)&Bs[kk][tx << 2];
            float a[4] = {av.x, av.y, av.z, av.w};
            float b[4] = {bv.x, bv.y, bv.z, bv.w};
            #pragma unroll
            for (int i = 0; i < 4; ++i)
                #pragma unroll
                for (int j = 0; j < 4; ++j)
                    acc[i][j] = fmaf(a[i], b[j], acc[i][j]);
        }
        __syncthreads();
    }

    // Epilogue: float4 stores (N is always a multiple of 4)
    const int gn0 = bn + (tx << 2);
    if (gn0 < N) {
        float4 bb = make_float4(0.f, 0.f, 0.f, 0.f);
        if (HAS_BIAS) bb = *(const float4*)&bias[gn0];
        #pragma unroll
        for (int i = 0; i < 4; ++i) {
            int gm = bm + (ty << 2) + i;
            if (gm >= M) continue;
            float4 v = make_float4(acc[i][0], acc[i][1], acc[i][2], acc[i][3]);
            if (HAS_BIAS) { v.x += bb.x; v.y += bb.y; v.z += bb.z; v.w += bb.w; }
            if (HAS_RES) {
                float4 rr = *(const float4*)&res[(size_t)gm * N + gn0];
                v.x += rr.x; v.y += rr.y; v.z += rr.z; v.w += rr.w;
            }
            if (ACT == 1) {
                v.x = softplus_f(v.x); v.y = softplus_f(v.y);
                v.z = softplus_f(v.z); v.w = softplus_f(v.w);
            }
            *(float4*)&C[(size_t)gm * N + gn0] = v;
        }
    }
}

// ---------------------------------------------------------------------------
// Launch: per block b:
//   H1 = softplus(X @ Wl[b]^T)            (K=168, N=256)
//   H2 = softplus(H1 @ Wl1[b]^T)          (K=256, N=256)
//   Y  = H2 @ Wvo[b]^T + bvo[b]   -> H1   (K=256, N=256)
//   X  = Xold + Y @ W20[b]^T              (K=256, N=168)
// out = X @ Wfc2^T                        (K=168, N=24)
// ---------------------------------------------------------------------------
extern "C" void kernel_launch(void* const* d_in, const int* in_sizes, int n_in,
                              void* d_out, int out_size, void* d_ws, size_t ws_size,
                              hipStream_t stream) {
    const float* x    = (const float*)d_in[0];
    const float* Wl   = (const float*)d_in[1];
    const float* Wl1  = (const float*)d_in[2];
    const float* Wv   = (const float*)d_in[7];
    const float* bv   = (const float*)d_in[8];
    const float* Wo   = (const float*)d_in[9];
    const float* bo   = (const float*)d_in[10];
    const float* W20  = (const float*)d_in[11];
    const float* Wfc2 = (const float*)d_in[12];
    float* out = (float*)d_out;

    float* ws  = (float*)d_ws;
    float* Wvo = ws;                                   // 3*256*256
    float* bvo = Wvo + NBLK * U_DIM * U_DIM;           // 3*256
    float* X   = bvo + NBLK * U_DIM;                   // 19000*168
    float* H1  = X  + (size_t)N_TS * T_DIM;            // 19000*256
    float* H2  = H1 + (size_t)N_TS * U_DIM;            // 19000*256

    precompute_kernel<<<dim3(NBLK * U_DIM), dim3(256), 0, stream>>>(
        Wv, bv, Wo, bo, Wvo, bvo);

    dim3 blk(256);
    dim3 gU((N_TS + 63) / 64, U_DIM / 64);             // 297 x 4
    dim3 gT((N_TS + 63) / 64, (T_DIM + 63) / 64);      // 297 x 3
    dim3 gH((N_TS + 63) / 64, 1);                      // 297 x 1

    const float* xsrc = x;
    for (int b = 0; b < NBLK; ++b) {
        gemm_nt<1, false, false><<<gU, blk, 0, stream>>>(
            xsrc, Wl + (size_t)b * U_DIM * T_DIM, nullptr, nullptr,
            H1, N_TS, U_DIM, T_DIM);
        gemm_nt<1, false, false><<<gU, blk, 0, stream>>>(
            H1, Wl1 + (size_t)b * U_DIM * U_DIM, nullptr, nullptr,
            H2, N_TS, U_DIM, U_DIM);
        gemm_nt<0, true, false><<<gU, blk, 0, stream>>>(
            H2, Wvo + (size_t)b * U_DIM * U_DIM, bvo + b * U_DIM, nullptr,
            H1, N_TS, U_DIM, U_DIM);                   // Y lives in H1
        gemm_nt<0, false, true><<<gT, blk, 0, stream>>>(
            H1, W20 + (size_t)b * T_DIM * U_DIM, nullptr, xsrc,
            X, N_TS, T_DIM, U_DIM);                    // X = xsrc + Y@W20^T
        xsrc = X;
    }
    gemm_nt<0, false, false><<<gH, blk, 0, stream>>>(
        X, Wfc2, nullptr, nullptr, out, N_TS, HORIZON, T_DIM);
}

// Round 2
// 341.255 us; speedup vs baseline: 1.9118x; 1.9118x over previous
//
#include <hip/hip_runtime.h>
#include <hip/hip_bf16.h>
#include <math.h>

#define N_TS   19000
#define M_PAD  19072      // 149 * 128
#define T_DIM  168
#define T_PAD  192        // 6 * 32
#define U_DIM  256
#define NBLK   3
#define HOR    24

using bf16 = __hip_bfloat16;
typedef short v8s __attribute__((ext_vector_type(8)));   // 8 bf16 = 4 VGPR (MFMA A/B frag)
typedef float v4f __attribute__((ext_vector_type(4)));   // MFMA C/D frag

__device__ __forceinline__ float softplus_f(float z) {
    return fmaxf(z, 0.0f) + log1pf(__expf(-fabsf(z)));
}

__device__ __forceinline__ void gload_lds16(const void* g, void* l) {
    __builtin_amdgcn_global_load_lds(
        (const __attribute__((address_space(1))) unsigned*)g,
        (__attribute__((address_space(3))) unsigned*)l, 16, 0, 0);
}

// ---------------------------------------------------------------------------
// Weight prep (one launch):
//  blocks [0,768):    Wvo[b] = Wo[b]@Wv[b] -> bf16; bvo = Wo@bv + bo (f32)
//  blocks [768,1536): Wl -> bf16, K-padded 168->192
//  blocks [1536,2304):Wl1 -> bf16
//  blocks [2304,2880):W20 -> bf16, N-padded rows 168->192 (zeros)
//  blocks [2880,2904):Wfc2 -> f32 copy, K-padded 168->192 (zeros)
// ---------------------------------------------------------------------------
__global__ __launch_bounds__(256) void wprep(
    const float* __restrict__ Wl, const float* __restrict__ Wl1,
    const float* __restrict__ Wv, const float* __restrict__ bv,
    const float* __restrict__ Wo, const float* __restrict__ bo,
    const float* __restrict__ W20, const float* __restrict__ Wfc2,
    bf16* __restrict__ Wlb, bf16* __restrict__ Wl1b, bf16* __restrict__ Wvob,
    bf16* __restrict__ W20b, float* __restrict__ Wfc2p, float* __restrict__ bvo)
{
    const int blk = blockIdx.x, j = threadIdx.x;
    if (blk < 768) {
        const int b = blk >> 8, n = blk & 255;
        const float* Wo_row = Wo + (size_t)(b * 256 + n) * 256;
        const float* Wv_b   = Wv + (size_t)b * 65536;
        float acc = 0.f;
        for (int t = 0; t < 256; ++t)
            acc = fmaf(Wo_row[t], Wv_b[(size_t)t * 256 + j], acc);
        Wvob[(size_t)(b * 256 + n) * 256 + j] = __float2bfloat16(acc);
        __shared__ float red[256];
        red[j] = Wo_row[j] * bv[b * 256 + j];
        __syncthreads();
        for (int s = 128; s > 0; s >>= 1) { if (j < s) red[j] += red[j + s]; __syncthreads(); }
        if (j == 0) bvo[b * 256 + n] = red[0] + bo[b * 256 + n];
    } else if (blk < 1536) {
        const int idx = blk - 768, b = idx >> 8, r = idx & 255;
        if (j < T_PAD)
            Wlb[(size_t)(b * 256 + r) * T_PAD + j] =
                __float2bfloat16(j < T_DIM ? Wl[(size_t)(b * 256 + r) * T_DIM + j] : 0.f);
    } else if (blk < 2304) {
        const int idx = blk - 1536, b = idx >> 8, r = idx & 255;
        Wl1b[(size_t)(b * 256 + r) * 256 + j] =
            __float2bfloat16(Wl1[(size_t)(b * 256 + r) * 256 + j]);
    } else if (blk < 2880) {
        const int idx = blk - 2304, b = idx / T_PAD, r = idx % T_PAD;
        W20b[(size_t)(b * T_PAD + r) * 256 + j] =
            __float2bfloat16(r < T_DIM ? W20[(size_t)(b * T_DIM + r) * 256 + j] : 0.f);
    } else {
        const int r = blk - 2880;
        if (j < T_PAD)
            Wfc2p[r * T_PAD + j] = (j < T_DIM) ? Wfc2[r * T_DIM + j] : 0.f;
    }
}

// x (f32, 19000x168) -> xb (bf16, padded 19072x192, zero-fill) + Xf (f32 same)
__global__ __launch_bounds__(256) void convert_x(
    const float* __restrict__ x, bf16* __restrict__ xb, float* __restrict__ Xf)
{
    const int i = blockIdx.x * 256 + threadIdx.x;   // < M_PAD*T_PAD (exact grid)
    const int r = i / T_PAD, c = i - r * T_PAD;
    const float v = (r < N_TS && c < T_DIM) ? x[(size_t)r * T_DIM + c] : 0.f;
    Xf[i] = v;
    xb[i] = __float2bfloat16(v);
}

// ---------------------------------------------------------------------------
// bf16 MFMA GEMM: C[M,N] = act( A[M,K] @ B[N,K]^T (+bias) ) (+res) -> f32/bf16
// BM=128, BN=64, BK=32, 256 threads = 4 waves (2x2), wave tile 64x32.
// All dims padded by caller: M=M_PAD multiple of 128, N multiple of 64,
// K multiple of 32. Row-major [row][32] LDS tiles, global_load_lds w=16.
// ---------------------------------------------------------------------------
template<int ACT, bool BIAS, bool RES, bool WF32, bool WB16>
__global__ __launch_bounds__(256) void gemm_mfma(
    const bf16* __restrict__ A, int lda,
    const bf16* __restrict__ B, int ldb,
    const float* __restrict__ bias,
    const float* __restrict__ res,
    float* __restrict__ Cf, bf16* __restrict__ Cb, int ldc,
    int K)
{
    __shared__ __align__(16) bf16 As[128 * 32];
    __shared__ __align__(16) bf16 Bs[64 * 32];

    const int tid  = threadIdx.x;
    const int lane = tid & 63, wave = tid >> 6;
    const int wr = wave >> 1, wc = wave & 1;
    const int bm = blockIdx.x * 128, bn = blockIdx.y * 64;

    v4f acc[4][2] = {};

    // staging map: chunk c covers row=c>>2, k-chunk=(c&3)*8 (16B each)
    const int cA0 = wave * 64 + lane;        // A chunks 0..255
    const int cA1 = cA0 + 256;               // A chunks 256..511
    const bf16* gA0 = A + (size_t)(bm + (cA0 >> 2)) * lda + (cA0 & 3) * 8;
    const bf16* gA1 = A + (size_t)(bm + (cA1 >> 2)) * lda + (cA1 & 3) * 8;
    const bf16* gB  = B + (size_t)(bn + (cA0 >> 2)) * ldb + (cA0 & 3) * 8;
    bf16* lA0 = As + (size_t)(wave * 64) * 8;         // wave-uniform bases
    bf16* lA1 = As + (size_t)(256 + wave * 64) * 8;
    bf16* lB  = Bs + (size_t)(wave * 64) * 8;

    // fragment read offsets (elements): row*32 + (lane>>4)*8
    const int a_off = (wr * 64 + (lane & 15)) * 32 + (lane >> 4) * 8;
    const int b_off = (wc * 32 + (lane & 15)) * 32 + (lane >> 4) * 8;

    for (int k0 = 0; k0 < K; k0 += 32) {
        gload_lds16(gA0 + k0, lA0);
        gload_lds16(gA1 + k0, lA1);
        gload_lds16(gB  + k0, lB);
        __syncthreads();
        v8s af[4], bf[2];
        #pragma unroll
        for (int m = 0; m < 4; ++m) af[m] = *(const v8s*)&As[a_off + m * 16 * 32];
        #pragma unroll
        for (int n = 0; n < 2; ++n) bf[n] = *(const v8s*)&Bs[b_off + n * 16 * 32];
        #pragma unroll
        for (int m = 0; m < 4; ++m)
            #pragma unroll
            for (int n = 0; n < 2; ++n)
                acc[m][n] = __builtin_amdgcn_mfma_f32_16x16x32_bf16(af[m], bf[n], acc[m][n], 0, 0, 0);
        __syncthreads();
    }

    // epilogue: D col = lane&15, row = 4*(lane>>4)+reg
    const int col0 = bn + wc * 32 + (lane & 15);
    const int row0 = bm + wr * 64 + (lane >> 4) * 4;
    #pragma unroll
    for (int n = 0; n < 2; ++n) {
        const int col = col0 + n * 16;
        const float bia = BIAS ? bias[col] : 0.f;
        #pragma unroll
        for (int m = 0; m < 4; ++m) {
            #pragma unroll
            for (int r = 0; r < 4; ++r) {
                const int row = row0 + m * 16 + r;
                float v = acc[m][n][r];
                if (BIAS) v += bia;
                if (ACT == 1) v = softplus_f(v);
                if (RES) v += res[(size_t)row * ldc + col];
                if (WF32) Cf[(size_t)row * ldc + col] = v;
                if (WB16) Cb[(size_t)row * ldc + col] = __float2bfloat16(v);
            }
        }
    }
}

// ---------------------------------------------------------------------------
// f32 VALU GEMM (round-1) — used only for the tiny final stage (N=24)
// ---------------------------------------------------------------------------
template<int ACT, bool HAS_BIAS, bool HAS_RES>
__global__ __launch_bounds__(256) void gemm_nt(
    const float* __restrict__ A, const float* __restrict__ B,
    const float* __restrict__ bias, const float* __restrict__ res,
    float* __restrict__ C, int M, int N, int K)
{
    constexpr int BM = 64, BN = 64, BK = 32;
    __shared__ float As[BK][BM + 4];
    __shared__ float Bs[BK][BN + 4];

    const int tid = threadIdx.x;
    const int tx = tid & 15, ty = tid >> 4;
    const int bm = blockIdx.x * BM, bn = blockIdx.y * BN;

    float acc[4][4] = {};
    const int nk = (K + BK - 1) / BK;
    for (int kt = 0; kt < nk; ++kt) {
        const int k0 = kt * BK;
        #pragma unroll
        for (int i = 0; i < 2; ++i) {
            int f = tid + i * 256, m = f >> 3, kq = (f & 7) << 2;
            int gm = bm + m, gk = k0 + kq;
            float4 v = make_float4(0.f, 0.f, 0.f, 0.f);
            if (gm < M && gk + 3 < K) v = *(const float4*)&A[(size_t)gm * K + gk];
            As[kq + 0][m] = v.x; As[kq + 1][m] = v.y; As[kq + 2][m] = v.z; As[kq + 3][m] = v.w;
        }
        #pragma unroll
        for (int i = 0; i < 2; ++i) {
            int f = tid + i * 256, n = f >> 3, kq = (f & 7) << 2;
            int gn = bn + n, gk = k0 + kq;
            float4 v = make_float4(0.f, 0.f, 0.f, 0.f);
            if (gn < N && gk + 3 < K) v = *(const float4*)&B[(size_t)gn * K + gk];
            Bs[kq + 0][n] = v.x; Bs[kq + 1][n] = v.y; Bs[kq + 2][n] = v.z; Bs[kq + 3][n] = v.w;
        }
        __syncthreads();
        #pragma unroll
        for (int kk = 0; kk < BK; ++kk) {
            float4 av = *(const float4*)&As[kk][ty << 2];
            float4 bv = *(const float4*)&Bs[kk][tx << 2];
            float a[4] = {av.x, av.y, av.z, av.w};
            float b[4] = {bv.x, bv.y, bv.z, bv.w};
            #pragma unroll
            for (int i = 0; i < 4; ++i)
                #pragma unroll
                for (int j = 0; j < 4; ++j)
                    acc[i][j] = fmaf(a[i], b[j], acc[i][j]);
        }
        __syncthreads();
    }
    const int gn0 = bn + (tx << 2);
    if (gn0 < N) {
        #pragma unroll
        for (int i = 0; i < 4; ++i) {
            int gm = bm + (ty << 2) + i;
            if (gm >= M) continue;
            float4 v = make_float4(acc[i][0], acc[i][1], acc[i][2], acc[i][3]);
            if (ACT == 1) {
                v.x = softplus_f(v.x); v.y = softplus_f(v.y);
                v.z = softplus_f(v.z); v.w = softplus_f(v.w);
            }
            *(float4*)&C[(size_t)gm * N + gn0] = v;
        }
    }
}

// ---------------------------------------------------------------------------
extern "C" void kernel_launch(void* const* d_in, const int* in_sizes, int n_in,
                              void* d_out, int out_size, void* d_ws, size_t ws_size,
                              hipStream_t stream) {
    const float* x    = (const float*)d_in[0];
    const float* Wl   = (const float*)d_in[1];
    const float* Wl1  = (const float*)d_in[2];
    const float* Wv   = (const float*)d_in[7];
    const float* bv   = (const float*)d_in[8];
    const float* Wo   = (const float*)d_in[9];
    const float* bo   = (const float*)d_in[10];
    const float* W20  = (const float*)d_in[11];
    const float* Wfc2 = (const float*)d_in[12];
    float* out = (float*)d_out;

    char* p = (char*)d_ws;
    auto carve = [&](size_t bytes) { char* q = p; p += (bytes + 255) & ~(size_t)255; return q; };
    bf16*  Wlb   = (bf16*)carve((size_t)NBLK * 256 * T_PAD * 2);
    bf16*  Wl1b  = (bf16*)carve((size_t)NBLK * 256 * 256 * 2);
    bf16*  Wvob  = (bf16*)carve((size_t)NBLK * 256 * 256 * 2);
    bf16*  W20b  = (bf16*)carve((size_t)NBLK * T_PAD * 256 * 2);
    float* Wfc2p = (float*)carve((size_t)HOR * T_PAD * 4);
    float* bvo   = (float*)carve((size_t)NBLK * 256 * 4);
    bf16*  xb    = (bf16*)carve((size_t)M_PAD * T_PAD * 2);   // doubles as Xb
    bf16*  h1b   = (bf16*)carve((size_t)M_PAD * 256 * 2);     // doubles as yb
    bf16*  h2b   = (bf16*)carve((size_t)M_PAD * 256 * 2);
    float* Xf    = (float*)carve((size_t)M_PAD * T_PAD * 4);  // f32 residual stream

    wprep<<<dim3(2904), dim3(256), 0, stream>>>(
        Wl, Wl1, Wv, bv, Wo, bo, W20, Wfc2, Wlb, Wl1b, Wvob, W20b, Wfc2p, bvo);
    convert_x<<<dim3((M_PAD * T_PAD) / 256), dim3(256), 0, stream>>>(x, xb, Xf);

    dim3 blk(256);
    dim3 gU(M_PAD / 128, U_DIM / 64);   // 149 x 4
    dim3 gT(M_PAD / 128, T_PAD / 64);   // 149 x 3
    for (int b = 0; b < NBLK; ++b) {
        // h1 = softplus(X @ Wl^T)
        gemm_mfma<1, false, false, false, true><<<gU, blk, 0, stream>>>(
            xb, T_PAD, Wlb + (size_t)b * 256 * T_PAD, T_PAD,
            nullptr, nullptr, nullptr, h1b, 256, T_PAD);
        // h2 = softplus(h1 @ Wl1^T)
        gemm_mfma<1, false, false, false, true><<<gU, blk, 0, stream>>>(
            h1b, 256, Wl1b + (size_t)b * 65536, 256,
            nullptr, nullptr, nullptr, h2b, 256, 256);
        // y = h2 @ Wvo^T + bvo   (into h1b)
        gemm_mfma<0, true, false, false, true><<<gU, blk, 0, stream>>>(
            h2b, 256, Wvob + (size_t)b * 65536, 256,
            bvo + b * 256, nullptr, nullptr, h1b, 256, 256);
        // X = X + y @ W20^T  (f32 residual in Xf, bf16 copy into xb for next block)
        gemm_mfma<0, false, true, true, true><<<gT, blk, 0, stream>>>(
            h1b, 256, W20b + (size_t)b * T_PAD * 256, 256,
            nullptr, Xf, Xf, xb, T_PAD, 256);
    }
    // out = X @ Wfc2^T  (f32, tiny)
    gemm_nt<0, false, false><<<dim3((N_TS + 63) / 64, 1), blk, 0, stream>>>(
        Xf, Wfc2p, nullptr, nullptr, out, N_TS, HOR, T_PAD);
}

// Round 3
// 340.860 us; speedup vs baseline: 1.9140x; 1.0012x over previous
//
#include <hip/hip_runtime.h>
#include <hip/hip_bf16.h>
#include <math.h>

#define N_TS   19000
#define M_PAD  19072      // 298 * 64
#define T_DIM  168
#define T_PAD  192        // 6 * 32
#define U_DIM  256
#define NBLK   3
#define HOR    24

using bf16 = __hip_bfloat16;
typedef short v8s __attribute__((ext_vector_type(8)));   // 8 bf16 (MFMA A/B frag)
typedef float v4f __attribute__((ext_vector_type(4)));   // MFMA C/D frag

__device__ __forceinline__ float softplus_f(float z) {
    return fmaxf(z, 0.0f) + log1pf(__expf(-fabsf(z)));
}
__device__ __forceinline__ unsigned pack2bf(float a, float b) {
    __hip_bfloat162 t = __float22bfloat162_rn(make_float2(a, b));
    return *(unsigned*)&t;
}
__device__ __forceinline__ short f2bf_s(float x) {
    bf16 h = __float2bfloat16(x); return *(short*)&h;
}
__device__ __forceinline__ v8s make_v8(float4 f0, float4 f1) {
    v8s r;
    r[0] = f2bf_s(f0.x); r[1] = f2bf_s(f0.y); r[2] = f2bf_s(f0.z); r[3] = f2bf_s(f0.w);
    r[4] = f2bf_s(f1.x); r[5] = f2bf_s(f1.y); r[6] = f2bf_s(f1.z); r[7] = f2bf_s(f1.w);
    return r;
}

// ---------------------------------------------------------------------------
// Weight prep:
//  [0,768):     Wvo[b] = Wo[b]@Wv[b] -> bf16; bvo = Wo@bv + bo (f32)
//  [768,1536):  Wl  -> bf16, K-pad 168->192
//  [1536,2304): Wl1 -> bf16
//  [2304,2880): W20 -> bf16, rows padded 168->192 (zeros)
//  [2880,2912): Wfc2 -> bf16, rows 24->32 (zeros), K-pad 168->192
// ---------------------------------------------------------------------------
__global__ __launch_bounds__(256) void wprep(
    const float* __restrict__ Wl, const float* __restrict__ Wl1,
    const float* __restrict__ Wv, const float* __restrict__ bv,
    const float* __restrict__ Wo, const float* __restrict__ bo,
    const float* __restrict__ W20, const float* __restrict__ Wfc2,
    bf16* __restrict__ Wlb, bf16* __restrict__ Wl1b, bf16* __restrict__ Wvob,
    bf16* __restrict__ W20b, bf16* __restrict__ Wfc2b, float* __restrict__ bvo)
{
    const int blk = blockIdx.x, j = threadIdx.x;
    if (blk < 768) {
        const int b = blk >> 8, n = blk & 255;
        const float* Wo_row = Wo + (size_t)(b * 256 + n) * 256;
        const float* Wv_b   = Wv + (size_t)b * 65536;
        float acc = 0.f;
        for (int t = 0; t < 256; ++t)
            acc = fmaf(Wo_row[t], Wv_b[(size_t)t * 256 + j], acc);
        Wvob[(size_t)(b * 256 + n) * 256 + j] = __float2bfloat16(acc);
        __shared__ float red[256];
        red[j] = Wo_row[j] * bv[b * 256 + j];
        __syncthreads();
        for (int s = 128; s > 0; s >>= 1) { if (j < s) red[j] += red[j + s]; __syncthreads(); }
        if (j == 0) bvo[b * 256 + n] = red[0] + bo[b * 256 + n];
    } else if (blk < 1536) {
        const int idx = blk - 768, b = idx >> 8, r = idx & 255;
        if (j < T_PAD)
            Wlb[(size_t)(b * 256 + r) * T_PAD + j] =
                __float2bfloat16(j < T_DIM ? Wl[(size_t)(b * 256 + r) * T_DIM + j] : 0.f);
    } else if (blk < 2304) {
        const int idx = blk - 1536, b = idx >> 8, r = idx & 255;
        Wl1b[(size_t)(b * 256 + r) * 256 + j] =
            __float2bfloat16(Wl1[(size_t)(b * 256 + r) * 256 + j]);
    } else if (blk < 2880) {
        const int idx = blk - 2304, b = idx / T_PAD, r = idx % T_PAD;
        W20b[(size_t)(b * T_PAD + r) * 256 + j] =
            __float2bfloat16(r < T_DIM ? W20[(size_t)(b * T_DIM + r) * 256 + j] : 0.f);
    } else {
        const int r = blk - 2880;   // 0..31
        if (j < T_PAD)
            Wfc2b[r * T_PAD + j] =
                __float2bfloat16((r < HOR && j < T_DIM) ? Wfc2[r * T_DIM + j] : 0.f);
    }
}

// x (f32, 19000x168) -> Xf (f32, padded 19072x192, zero-fill)
__global__ __launch_bounds__(256) void convert_x(
    const float* __restrict__ x, float* __restrict__ Xf)
{
    const int i = blockIdx.x * 256 + threadIdx.x;
    const int r = i / T_PAD, c = i - r * T_PAD;
    Xf[i] = (r < N_TS && c < T_DIM) ? x[(size_t)r * T_DIM + c] : 0.f;
}

// ---------------------------------------------------------------------------
// Fused network kernel. 64 rows/block, 4 waves; wave w owns h-cols [64w,64w+64).
// Swapped MFMA: A = weight rows (global, L2-hot), B = activation rows.
// D[row=i=w-row=h-col][col=j=act-row]: lane holds h[row=16j+(lane&15)]
// [cols 64w+16i+4*(lane>>4)+r], r=0..3 -> contiguous 4-col ds_write_b64.
// LDS h layout: elem (row,col) at byte row*512 + ((2*col) ^ ((row&7)<<4)).
// ---------------------------------------------------------------------------
template<bool SP, bool BIAS>
__device__ __forceinline__ void epi_store(v4f acc[4][4], const float* bias,
                                          bf16* dst, int w, int r16, int kq)
{
    #pragma unroll
    for (int i = 0; i < 4; ++i) {
        float4 bb = make_float4(0.f, 0.f, 0.f, 0.f);
        if (BIAS) bb = *(const float4*)&bias[64 * w + 16 * i + 4 * kq];
        #pragma unroll
        for (int j = 0; j < 4; ++j) {
            float v0 = acc[i][j][0], v1 = acc[i][j][1], v2 = acc[i][j][2], v3 = acc[i][j][3];
            if (BIAS) { v0 += bb.x; v1 += bb.y; v2 += bb.z; v3 += bb.w; }
            if (SP) { v0 = softplus_f(v0); v1 = softplus_f(v1);
                      v2 = softplus_f(v2); v3 = softplus_f(v3); }
            const int row = 16 * j + r16;
            const int c0  = 64 * w + 16 * i + 4 * kq;
            const int off = row * 512 + ((2 * c0) ^ ((row & 7) << 4));
            *(uint2*)((char*)dst + off) = make_uint2(pack2bf(v0, v1), pack2bf(v2, v3));
        }
    }
}

template<bool SP, bool BIAS>
__device__ __forceinline__ void gemm_h2h(const bf16* __restrict__ W,
                                         const float* __restrict__ bias,
                                         const bf16* src, bf16* dst,
                                         int w, int r16, int kq)
{
    v4f acc[4][4] = {};
    #pragma unroll 2
    for (int ks = 0; ks < 8; ++ks) {
        v8s a[4], bfr[4];
        #pragma unroll
        for (int i = 0; i < 4; ++i)
            a[i] = *(const v8s*)&W[(size_t)(64 * w + 16 * i + r16) * 256 + ks * 32 + 8 * kq];
        #pragma unroll
        for (int j = 0; j < 4; ++j) {
            const int row = 16 * j + r16;
            bfr[j] = *(const v8s*)((const char*)src + row * 512 +
                                   ((ks * 64 + 16 * kq) ^ ((row & 7) << 4)));
        }
        #pragma unroll
        for (int i = 0; i < 4; ++i)
            #pragma unroll
            for (int j = 0; j < 4; ++j)
                acc[i][j] = __builtin_amdgcn_mfma_f32_16x16x32_bf16(a[i], bfr[j], acc[i][j], 0, 0, 0);
    }
    epi_store<SP, BIAS>(acc, bias, dst, w, r16, kq);
}

__global__ __launch_bounds__(256, 2) void fused_net(
    const bf16* __restrict__ Wlb, const bf16* __restrict__ Wl1b,
    const bf16* __restrict__ Wvob, const bf16* __restrict__ W20b,
    const bf16* __restrict__ Wfc2b, const float* __restrict__ bvo,
    float* __restrict__ Xf, float* __restrict__ out)
{
    __shared__ __align__(16) bf16 hA[64 * 256];
    __shared__ __align__(16) bf16 hB[64 * 256];

    const int tid  = threadIdx.x;
    const int lane = tid & 63, w = tid >> 6;
    const int r16  = lane & 15, kq = lane >> 4;
    const int bm   = blockIdx.x * 64;

    for (int b = 0; b < NBLK; ++b) {
        // ---- GEMM1: hA = softplus(X @ Wl^T), K=192, B-frags from global f32 ----
        {
            const bf16* W = Wlb + (size_t)b * 256 * T_PAD;
            v4f acc[4][4] = {};
            #pragma unroll 2
            for (int ks = 0; ks < 6; ++ks) {
                v8s a[4], bfr[4];
                #pragma unroll
                for (int i = 0; i < 4; ++i)
                    a[i] = *(const v8s*)&W[(size_t)(64 * w + 16 * i + r16) * T_PAD + ks * 32 + 8 * kq];
                #pragma unroll
                for (int j = 0; j < 4; ++j) {
                    const float* xr = Xf + (size_t)(bm + 16 * j + r16) * T_PAD + ks * 32 + 8 * kq;
                    float4 f0 = *(const float4*)xr;
                    float4 f1 = *(const float4*)(xr + 4);
                    bfr[j] = make_v8(f0, f1);
                }
                #pragma unroll
                for (int i = 0; i < 4; ++i)
                    #pragma unroll
                    for (int j = 0; j < 4; ++j)
                        acc[i][j] = __builtin_amdgcn_mfma_f32_16x16x32_bf16(a[i], bfr[j], acc[i][j], 0, 0, 0);
            }
            epi_store<true, false>(acc, nullptr, hA, w, r16, kq);
        }
        __syncthreads();
        // ---- GEMM2: hB = softplus(hA @ Wl1^T) ----
        gemm_h2h<true, false>(Wl1b + (size_t)b * 65536, nullptr, hA, hB, w, r16, kq);
        __syncthreads();
        // ---- GEMM3: hA = hB @ Wvo^T + bvo ----
        gemm_h2h<false, true>(Wvob + (size_t)b * 65536, bvo + b * 256, hB, hA, w, r16, kq);
        __syncthreads();
        // ---- GEMM4: Xf += hA @ W20^T (f32 in-place; wave w owns x-cols [48w,48w+48)) ----
        {
            const bf16* W = W20b + (size_t)b * T_PAD * 256;
            v4f acc[3][4] = {};
            #pragma unroll 2
            for (int ks = 0; ks < 8; ++ks) {
                v8s a[3], bfr[4];
                #pragma unroll
                for (int i = 0; i < 3; ++i)
                    a[i] = *(const v8s*)&W[(size_t)(48 * w + 16 * i + r16) * 256 + ks * 32 + 8 * kq];
                #pragma unroll
                for (int j = 0; j < 4; ++j) {
                    const int row = 16 * j + r16;
                    bfr[j] = *(const v8s*)((const char*)hA + row * 512 +
                                           ((ks * 64 + 16 * kq) ^ ((row & 7) << 4)));
                }
                #pragma unroll
                for (int i = 0; i < 3; ++i)
                    #pragma unroll
                    for (int j = 0; j < 4; ++j)
                        acc[i][j] = __builtin_amdgcn_mfma_f32_16x16x32_bf16(a[i], bfr[j], acc[i][j], 0, 0, 0);
            }
            #pragma unroll
            for (int i = 0; i < 3; ++i)
                #pragma unroll
                for (int j = 0; j < 4; ++j) {
                    const int row = bm + 16 * j + r16;
                    const int c0  = 48 * w + 16 * i + 4 * kq;
                    float4* p = (float4*)&Xf[(size_t)row * T_PAD + c0];
                    float4 v = *p;
                    v.x += acc[i][j][0]; v.y += acc[i][j][1];
                    v.z += acc[i][j][2]; v.w += acc[i][j][3];
                    *p = v;
                }
        }
        __syncthreads();
    }

    // ---- fc2: out = X @ Wfc2^T (K=192, 32 padded out-cols; wave w owns rows 16w..16w+15) ----
    {
        v4f acc0 = {}, acc1 = {};
        #pragma unroll
        for (int ks = 0; ks < 6; ++ks) {
            v8s a0 = *(const v8s*)&Wfc2b[(size_t)(r16) * T_PAD + ks * 32 + 8 * kq];
            v8s a1 = *(const v8s*)&Wfc2b[(size_t)(16 + r16) * T_PAD + ks * 32 + 8 * kq];
            const float* xr = Xf + (size_t)(bm + 16 * w + r16) * T_PAD + ks * 32 + 8 * kq;
            float4 f0 = *(const float4*)xr;
            float4 f1 = *(const float4*)(xr + 4);
            v8s xb_ = make_v8(f0, f1);
            acc0 = __builtin_amdgcn_mfma_f32_16x16x32_bf16(a0, xb_, acc0, 0, 0, 0);
            acc1 = __builtin_amdgcn_mfma_f32_16x16x32_bf16(a1, xb_, acc1, 0, 0, 0);
        }
        const int orow = bm + 16 * w + r16;
        if (orow < N_TS) {
            float4 v0 = make_float4(acc0[0], acc0[1], acc0[2], acc0[3]);
            *(float4*)&out[(size_t)orow * HOR + 4 * kq] = v0;
            if (kq < 2) {
                float4 v1 = make_float4(acc1[0], acc1[1], acc1[2], acc1[3]);
                *(float4*)&out[(size_t)orow * HOR + 16 + 4 * kq] = v1;
            }
        }
    }
}

// ---------------------------------------------------------------------------
extern "C" void kernel_launch(void* const* d_in, const int* in_sizes, int n_in,
                              void* d_out, int out_size, void* d_ws, size_t ws_size,
                              hipStream_t stream) {
    const float* x    = (const float*)d_in[0];
    const float* Wl   = (const float*)d_in[1];
    const float* Wl1  = (const float*)d_in[2];
    const float* Wv   = (const float*)d_in[7];
    const float* bv   = (const float*)d_in[8];
    const float* Wo   = (const float*)d_in[9];
    const float* bo   = (const float*)d_in[10];
    const float* W20  = (const float*)d_in[11];
    const float* Wfc2 = (const float*)d_in[12];
    float* out = (float*)d_out;

    char* p = (char*)d_ws;
    auto carve = [&](size_t bytes) { char* q = p; p += (bytes + 255) & ~(size_t)255; return q; };
    bf16*  Wlb   = (bf16*)carve((size_t)NBLK * 256 * T_PAD * 2);
    bf16*  Wl1b  = (bf16*)carve((size_t)NBLK * 256 * 256 * 2);
    bf16*  Wvob  = (bf16*)carve((size_t)NBLK * 256 * 256 * 2);
    bf16*  W20b  = (bf16*)carve((size_t)NBLK * T_PAD * 256 * 2);
    bf16*  Wfc2b = (bf16*)carve((size_t)32 * T_PAD * 2);
    float* bvo   = (float*)carve((size_t)NBLK * 256 * 4);
    float* Xf    = (float*)carve((size_t)M_PAD * T_PAD * 4);

    wprep<<<dim3(2912), dim3(256), 0, stream>>>(
        Wl, Wl1, Wv, bv, Wo, bo, W20, Wfc2, Wlb, Wl1b, Wvob, W20b, Wfc2b, bvo);
    convert_x<<<dim3((M_PAD * T_PAD) / 256), dim3(256), 0, stream>>>(x, Xf);
    fused_net<<<dim3(M_PAD / 64), dim3(256), 0, stream>>>(
        Wlb, Wl1b, Wvob, W20b, Wfc2b, bvo, Xf, out);
}

// Round 4
// 252.286 us; speedup vs baseline: 2.5860x; 1.3511x over previous
//
#include <hip/hip_runtime.h>
#include <hip/hip_bf16.h>
#include <math.h>

#define N_TS   19000
#define M_PAD  19072      // 596 * 32
#define ROWS   32         // rows per block
#define T_DIM  168
#define T_PAD  192        // 6 * 32
#define U_DIM  256
#define NBLK   3
#define HOR    24

using bf16 = __hip_bfloat16;
typedef short v8s __attribute__((ext_vector_type(8)));   // 8 bf16 (MFMA A/B frag)
typedef float v4f __attribute__((ext_vector_type(4)));   // MFMA C/D frag

// fast softplus: max(z,0) + log(1+exp(-|z|)) with native exp/log.
// |err| vs log1pf path <= ~6e-8, invisible at bf16 storage precision.
__device__ __forceinline__ float softplus_f(float z) {
    return fmaxf(z, 0.0f) + __logf(1.0f + __expf(-fabsf(z)));
}
__device__ __forceinline__ unsigned pack2bf(float a, float b) {
    __hip_bfloat162 t = __float22bfloat162_rn(make_float2(a, b));
    return *(unsigned*)&t;
}
__device__ __forceinline__ short f2bf_s(float x) {
    bf16 h = __float2bfloat16(x); return *(short*)&h;
}
__device__ __forceinline__ v8s make_v8(float4 f0, float4 f1) {
    v8s r;
    r[0] = f2bf_s(f0.x); r[1] = f2bf_s(f0.y); r[2] = f2bf_s(f0.z); r[3] = f2bf_s(f0.w);
    r[4] = f2bf_s(f1.x); r[5] = f2bf_s(f1.y); r[6] = f2bf_s(f1.z); r[7] = f2bf_s(f1.w);
    return r;
}

// ---------------------------------------------------------------------------
// Weight prep (same as round 3):
//  [0,768):     Wvo[b] = Wo[b]@Wv[b] -> bf16; bvo = Wo@bv + bo (f32)
//  [768,1536):  Wl  -> bf16, K-pad 168->192
//  [1536,2304): Wl1 -> bf16
//  [2304,2880): W20 -> bf16, rows padded 168->192 (zeros)
//  [2880,2912): Wfc2 -> bf16, rows 24->32 (zeros), K-pad 168->192
// ---------------------------------------------------------------------------
__global__ __launch_bounds__(256) void wprep(
    const float* __restrict__ Wl, const float* __restrict__ Wl1,
    const float* __restrict__ Wv, const float* __restrict__ bv,
    const float* __restrict__ Wo, const float* __restrict__ bo,
    const float* __restrict__ W20, const float* __restrict__ Wfc2,
    bf16* __restrict__ Wlb, bf16* __restrict__ Wl1b, bf16* __restrict__ Wvob,
    bf16* __restrict__ W20b, bf16* __restrict__ Wfc2b, float* __restrict__ bvo)
{
    const int blk = blockIdx.x, j = threadIdx.x;
    if (blk < 768) {
        const int b = blk >> 8, n = blk & 255;
        const float* Wo_row = Wo + (size_t)(b * 256 + n) * 256;
        const float* Wv_b   = Wv + (size_t)b * 65536;
        float acc = 0.f;
        for (int t = 0; t < 256; ++t)
            acc = fmaf(Wo_row[t], Wv_b[(size_t)t * 256 + j], acc);
        Wvob[(size_t)(b * 256 + n) * 256 + j] = __float2bfloat16(acc);
        __shared__ float red[256];
        red[j] = Wo_row[j] * bv[b * 256 + j];
        __syncthreads();
        for (int s = 128; s > 0; s >>= 1) { if (j < s) red[j] += red[j + s]; __syncthreads(); }
        if (j == 0) bvo[b * 256 + n] = red[0] + bo[b * 256 + n];
    } else if (blk < 1536) {
        const int idx = blk - 768, b = idx >> 8, r = idx & 255;
        if (j < T_PAD)
            Wlb[(size_t)(b * 256 + r) * T_PAD + j] =
                __float2bfloat16(j < T_DIM ? Wl[(size_t)(b * 256 + r) * T_DIM + j] : 0.f);
    } else if (blk < 2304) {
        const int idx = blk - 1536, b = idx >> 8, r = idx & 255;
        Wl1b[(size_t)(b * 256 + r) * 256 + j] =
            __float2bfloat16(Wl1[(size_t)(b * 256 + r) * 256 + j]);
    } else if (blk < 2880) {
        const int idx = blk - 2304, b = idx / T_PAD, r = idx % T_PAD;
        W20b[(size_t)(b * T_PAD + r) * 256 + j] =
            __float2bfloat16(r < T_DIM ? W20[(size_t)(b * T_DIM + r) * 256 + j] : 0.f);
    } else {
        const int r = blk - 2880;   // 0..31
        if (j < T_PAD)
            Wfc2b[r * T_PAD + j] =
                __float2bfloat16((r < HOR && j < T_DIM) ? Wfc2[r * T_DIM + j] : 0.f);
    }
}

// x (f32, 19000x168) -> Xf (f32, padded 19072x192, zero-fill)
__global__ __launch_bounds__(256) void convert_x(
    const float* __restrict__ x, float* __restrict__ Xf)
{
    const int i = blockIdx.x * 256 + threadIdx.x;
    const int r = i / T_PAD, c = i - r * T_PAD;
    Xf[i] = (r < N_TS && c < T_DIM) ? x[(size_t)r * T_DIM + c] : 0.f;
}

// ---------------------------------------------------------------------------
// Fused network. ROWS=32 rows/block, 4 waves; wave w owns h-cols [64w,64w+64).
// Swapped MFMA: A = weight rows (global, L2-hot), B = activation rows.
// LDS h layout: elem (row,col) at byte row*512 + ((2*col) ^ ((row&7)<<4)).
// D frag: lane holds h[row=16j+(lane&15)][cols NI*16*w+16i+4*(lane>>4)+r].
// ---------------------------------------------------------------------------
template<int NI, bool SP, bool BIAS>
__device__ __forceinline__ void epi_store(v4f acc[NI][2], const float* bias,
                                          bf16* dst, int w, int r16, int kq)
{
    #pragma unroll
    for (int i = 0; i < NI; ++i) {
        float4 bb = make_float4(0.f, 0.f, 0.f, 0.f);
        if (BIAS) bb = *(const float4*)&bias[NI * 16 * w + 16 * i + 4 * kq];
        #pragma unroll
        for (int j = 0; j < 2; ++j) {
            float v0 = acc[i][j][0], v1 = acc[i][j][1], v2 = acc[i][j][2], v3 = acc[i][j][3];
            if (BIAS) { v0 += bb.x; v1 += bb.y; v2 += bb.z; v3 += bb.w; }
            if (SP) { v0 = softplus_f(v0); v1 = softplus_f(v1);
                      v2 = softplus_f(v2); v3 = softplus_f(v3); }
            const int row = 16 * j + r16;
            const int c0  = NI * 16 * w + 16 * i + 4 * kq;
            const int off = row * 512 + ((2 * c0) ^ ((row & 7) << 4));
            *(uint2*)((char*)dst + off) = make_uint2(pack2bf(v0, v1), pack2bf(v2, v3));
        }
    }
}

template<bool SP, bool BIAS>
__device__ __forceinline__ void gemm_h2h(const bf16* __restrict__ W,
                                         const float* __restrict__ bias,
                                         const bf16* src, bf16* dst,
                                         int w, int r16, int kq)
{
    v4f acc[4][2] = {};
    #pragma unroll 2
    for (int ks = 0; ks < 8; ++ks) {
        v8s a[4], bfr[2];
        #pragma unroll
        for (int i = 0; i < 4; ++i)
            a[i] = *(const v8s*)&W[(size_t)(64 * w + 16 * i + r16) * 256 + ks * 32 + 8 * kq];
        #pragma unroll
        for (int j = 0; j < 2; ++j) {
            const int row = 16 * j + r16;
            bfr[j] = *(const v8s*)((const char*)src + row * 512 +
                                   ((ks * 64 + 16 * kq) ^ ((row & 7) << 4)));
        }
        #pragma unroll
        for (int i = 0; i < 4; ++i)
            #pragma unroll
            for (int j = 0; j < 2; ++j)
                acc[i][j] = __builtin_amdgcn_mfma_f32_16x16x32_bf16(a[i], bfr[j], acc[i][j], 0, 0, 0);
    }
    epi_store<4, SP, BIAS>(acc, bias, dst, w, r16, kq);
}

__global__ __launch_bounds__(256, 3) void fused_net(
    const bf16* __restrict__ Wlb, const bf16* __restrict__ Wl1b,
    const bf16* __restrict__ Wvob, const bf16* __restrict__ W20b,
    const bf16* __restrict__ Wfc2b, const float* __restrict__ bvo,
    float* __restrict__ Xf, float* __restrict__ out)
{
    __shared__ __align__(16) bf16 hA[ROWS * 256];
    __shared__ __align__(16) bf16 hB[ROWS * 256];

    const int tid  = threadIdx.x;
    const int lane = tid & 63, w = tid >> 6;
    const int r16  = lane & 15, kq = lane >> 4;
    const int bm   = blockIdx.x * ROWS;

    for (int b = 0; b < NBLK; ++b) {
        // ---- GEMM1: hA = softplus(X @ Wl^T), K=192, B-frags from global f32 ----
        {
            const bf16* W = Wlb + (size_t)b * 256 * T_PAD;
            v4f acc[4][2] = {};
            #pragma unroll 2
            for (int ks = 0; ks < 6; ++ks) {
                v8s a[4], bfr[2];
                #pragma unroll
                for (int i = 0; i < 4; ++i)
                    a[i] = *(const v8s*)&W[(size_t)(64 * w + 16 * i + r16) * T_PAD + ks * 32 + 8 * kq];
                #pragma unroll
                for (int j = 0; j < 2; ++j) {
                    const float* xr = Xf + (size_t)(bm + 16 * j + r16) * T_PAD + ks * 32 + 8 * kq;
                    float4 f0 = *(const float4*)xr;
                    float4 f1 = *(const float4*)(xr + 4);
                    bfr[j] = make_v8(f0, f1);
                }
                #pragma unroll
                for (int i = 0; i < 4; ++i)
                    #pragma unroll
                    for (int j = 0; j < 2; ++j)
                        acc[i][j] = __builtin_amdgcn_mfma_f32_16x16x32_bf16(a[i], bfr[j], acc[i][j], 0, 0, 0);
            }
            epi_store<4, true, false>(acc, nullptr, hA, w, r16, kq);
        }
        __syncthreads();
        // ---- GEMM2: hB = softplus(hA @ Wl1^T) ----
        gemm_h2h<true, false>(Wl1b + (size_t)b * 65536, nullptr, hA, hB, w, r16, kq);
        __syncthreads();
        // ---- GEMM3: hA = hB @ Wvo^T + bvo ----
        gemm_h2h<false, true>(Wvob + (size_t)b * 65536, bvo + b * 256, hB, hA, w, r16, kq);
        __syncthreads();
        // ---- GEMM4: Xf += hA @ W20^T (wave w owns x-cols [48w,48w+48)) ----
        {
            const bf16* W = W20b + (size_t)b * T_PAD * 256;
            v4f acc[3][2] = {};
            #pragma unroll 2
            for (int ks = 0; ks < 8; ++ks) {
                v8s a[3], bfr[2];
                #pragma unroll
                for (int i = 0; i < 3; ++i)
                    a[i] = *(const v8s*)&W[(size_t)(48 * w + 16 * i + r16) * 256 + ks * 32 + 8 * kq];
                #pragma unroll
                for (int j = 0; j < 2; ++j) {
                    const int row = 16 * j + r16;
                    bfr[j] = *(const v8s*)((const char*)hA + row * 512 +
                                           ((ks * 64 + 16 * kq) ^ ((row & 7) << 4)));
                }
                #pragma unroll
                for (int i = 0; i < 3; ++i)
                    #pragma unroll
                    for (int j = 0; j < 2; ++j)
                        acc[i][j] = __builtin_amdgcn_mfma_f32_16x16x32_bf16(a[i], bfr[j], acc[i][j], 0, 0, 0);
            }
            #pragma unroll
            for (int i = 0; i < 3; ++i)
                #pragma unroll
                for (int j = 0; j < 2; ++j) {
                    const int row = bm + 16 * j + r16;
                    const int c0  = 48 * w + 16 * i + 4 * kq;
                    float4* p = (float4*)&Xf[(size_t)row * T_PAD + c0];
                    float4 v = *p;
                    v.x += acc[i][j][0]; v.y += acc[i][j][1];
                    v.z += acc[i][j][2]; v.w += acc[i][j][3];
                    *p = v;
                }
        }
        __syncthreads();
    }

    // ---- fc2: out = X @ Wfc2^T (waves 0,1 handle 16 rows each) ----
    if (w < 2) {
        v4f acc0 = {}, acc1 = {};
        #pragma unroll
        for (int ks = 0; ks < 6; ++ks) {
            v8s a0 = *(const v8s*)&Wfc2b[(size_t)(r16) * T_PAD + ks * 32 + 8 * kq];
            v8s a1 = *(const v8s*)&Wfc2b[(size_t)(16 + r16) * T_PAD + ks * 32 + 8 * kq];
            const float* xr = Xf + (size_t)(bm + 16 * w + r16) * T_PAD + ks * 32 + 8 * kq;
            float4 f0 = *(const float4*)xr;
            float4 f1 = *(const float4*)(xr + 4);
            v8s xb_ = make_v8(f0, f1);
            acc0 = __builtin_amdgcn_mfma_f32_16x16x32_bf16(a0, xb_, acc0, 0, 0, 0);
            acc1 = __builtin_amdgcn_mfma_f32_16x16x32_bf16(a1, xb_, acc1, 0, 0, 0);
        }
        const int orow = bm + 16 * w + r16;
        if (orow < N_TS) {
            float4 v0 = make_float4(acc0[0], acc0[1], acc0[2], acc0[3]);
            *(float4*)&out[(size_t)orow * HOR + 4 * kq] = v0;
            if (kq < 2) {
                float4 v1 = make_float4(acc1[0], acc1[1], acc1[2], acc1[3]);
                *(float4*)&out[(size_t)orow * HOR + 16 + 4 * kq] = v1;
            }
        }
    }
}

// ---------------------------------------------------------------------------
extern "C" void kernel_launch(void* const* d_in, const int* in_sizes, int n_in,
                              void* d_out, int out_size, void* d_ws, size_t ws_size,
                              hipStream_t stream) {
    const float* x    = (const float*)d_in[0];
    const float* Wl   = (const float*)d_in[1];
    const float* Wl1  = (const float*)d_in[2];
    const float* Wv   = (const float*)d_in[7];
    const float* bv   = (const float*)d_in[8];
    const float* Wo   = (const float*)d_in[9];
    const float* bo   = (const float*)d_in[10];
    const float* W20  = (const float*)d_in[11];
    const float* Wfc2 = (const float*)d_in[12];
    float* out = (float*)d_out;

    char* p = (char*)d_ws;
    auto carve = [&](size_t bytes) { char* q = p; p += (bytes + 255) & ~(size_t)255; return q; };
    bf16*  Wlb   = (bf16*)carve((size_t)NBLK * 256 * T_PAD * 2);
    bf16*  Wl1b  = (bf16*)carve((size_t)NBLK * 256 * 256 * 2);
    bf16*  Wvob  = (bf16*)carve((size_t)NBLK * 256 * 256 * 2);
    bf16*  W20b  = (bf16*)carve((size_t)NBLK * T_PAD * 256 * 2);
    bf16*  Wfc2b = (bf16*)carve((size_t)32 * T_PAD * 2);
    float* bvo   = (float*)carve((size_t)NBLK * 256 * 4);
    float* Xf    = (float*)carve((size_t)M_PAD * T_PAD * 4);

    wprep<<<dim3(2912), dim3(256), 0, stream>>>(
        Wl, Wl1, Wv, bv, Wo, bo, W20, Wfc2, Wlb, Wl1b, Wvob, W20b, Wfc2b, bvo);
    convert_x<<<dim3((M_PAD * T_PAD) / 256), dim3(256), 0, stream>>>(x, Xf);
    fused_net<<<dim3(M_PAD / ROWS), dim3(256), 0, stream>>>(
        Wlb, Wl1b, Wvob, W20b, Wfc2b, bvo, Xf, out);
}